// Round 1
// baseline (169.642 us; speedup 1.0000x reference)
//
#include <hip/hip_runtime.h>
#include <hip/hip_bf16.h>

#define D 256
#define NROWS 8192
#define LBATCH 4096

typedef unsigned int u32;
typedef unsigned short u16;

__device__ __forceinline__ float bflo(u32 w) { return __uint_as_float(w << 16); }
__device__ __forceinline__ float bfhi(u32 w) { return __uint_as_float(w & 0xffff0000u); }
__device__ __forceinline__ u16 f2bf(float f) {
    u32 x = __float_as_uint(f);
    x += 0x7fffu + ((x >> 16) & 1u);
    return (u16)(x >> 16);
}

// ---------------- Kernel 1: fused QKV projection ----------------
// C[8192 x 768] = H[8192 x 256] @ [Wq|Wk|Wv] + [bq|bk|bv], stored bf16.
__global__ __launch_bounds__(256) void qkv_proj(
    const float* __restrict__ H,
    const float* __restrict__ Wq, const float* __restrict__ bq,
    const float* __restrict__ Wk, const float* __restrict__ bk,
    const float* __restrict__ Wv, const float* __restrict__ bv,
    u16* __restrict__ Qb, u16* __restrict__ Kb, u16* __restrict__ Vb)
{
    __shared__ float As[64][37];   // [m][k], pad 37 -> 2-way max on column reads
    __shared__ float Bs[32][64];   // [k][n]

    const int tid = threadIdx.x;
    const int bx = blockIdx.x;     // 0..11 (col tiles of 64 over 768)
    const int by = blockIdx.y;     // 0..127 (row tiles of 64)
    const int row0 = by * 64;
    const int mat = bx >> 2;                 // 0=Q 1=K 2=V
    const int coln0 = (bx & 3) * 64;         // col offset within the 256-col matrix
    const float* __restrict__ W    = (mat == 0) ? Wq : (mat == 1) ? Wk : Wv;
    const float* __restrict__ bias = (mat == 0) ? bq : (mat == 1) ? bk : bv;
    u16* __restrict__ dst          = (mat == 0) ? Qb : (mat == 1) ? Kb : Vb;

    const int tr = tid >> 4, tc = tid & 15;
    const int a_r = tid >> 2, a_k0 = (tid & 3) * 8;
    const int b_k = tid >> 3, b_c0 = (tid & 7) * 8;

    float acc[4][4] = {};

    for (int kb = 0; kb < D; kb += 32) {
        float4 av0 = *(const float4*)&H[(row0 + a_r) * D + kb + a_k0];
        float4 av1 = *(const float4*)&H[(row0 + a_r) * D + kb + a_k0 + 4];
        float4 bw0 = *(const float4*)&W[(kb + b_k) * D + coln0 + b_c0];
        float4 bw1 = *(const float4*)&W[(kb + b_k) * D + coln0 + b_c0 + 4];
        As[a_r][a_k0 + 0] = av0.x; As[a_r][a_k0 + 1] = av0.y;
        As[a_r][a_k0 + 2] = av0.z; As[a_r][a_k0 + 3] = av0.w;
        As[a_r][a_k0 + 4] = av1.x; As[a_r][a_k0 + 5] = av1.y;
        As[a_r][a_k0 + 6] = av1.z; As[a_r][a_k0 + 7] = av1.w;
        *(float4*)&Bs[b_k][b_c0] = bw0;
        *(float4*)&Bs[b_k][b_c0 + 4] = bw1;
        __syncthreads();
        #pragma unroll 8
        for (int kk = 0; kk < 32; ++kk) {
            float a0 = As[tr * 4 + 0][kk];
            float a1 = As[tr * 4 + 1][kk];
            float a2 = As[tr * 4 + 2][kk];
            float a3 = As[tr * 4 + 3][kk];
            float4 b4 = *(const float4*)&Bs[kk][tc * 4];
            acc[0][0] += a0 * b4.x; acc[0][1] += a0 * b4.y; acc[0][2] += a0 * b4.z; acc[0][3] += a0 * b4.w;
            acc[1][0] += a1 * b4.x; acc[1][1] += a1 * b4.y; acc[1][2] += a1 * b4.z; acc[1][3] += a1 * b4.w;
            acc[2][0] += a2 * b4.x; acc[2][1] += a2 * b4.y; acc[2][2] += a2 * b4.z; acc[2][3] += a2 * b4.w;
            acc[3][0] += a3 * b4.x; acc[3][1] += a3 * b4.y; acc[3][2] += a3 * b4.z; acc[3][3] += a3 * b4.w;
        }
        __syncthreads();
    }

    #pragma unroll
    for (int ri = 0; ri < 4; ++ri) {
        const int row = row0 + tr * 4 + ri;
        const int col = coln0 + tc * 4;
        float4 bia = *(const float4*)&bias[col];
        u32 p0 = (u32)f2bf(acc[ri][0] + bia.x) | ((u32)f2bf(acc[ri][1] + bia.y) << 16);
        u32 p1 = (u32)f2bf(acc[ri][2] + bia.z) | ((u32)f2bf(acc[ri][3] + bia.w) << 16);
        uint2 o; o.x = p0; o.y = p1;
        *(uint2*)&dst[row * D + col] = o;
    }
}

// ---------------- Kernel 2: fused 3-window attention ----------------
// Per row l: s_j = dot(Q[l], K[l-63+j])/16 (virtual key = bk for OOR),
// combined softmax weights for windows {64,16,4}, merged = sum_j w_j * V.
#define KROWS 79
#define KSTR 266   // 532B row stride = 133 dwords == 5 (mod 32): conflict-free

__global__ __launch_bounds__(256) void attn_kernel(
    const u16* __restrict__ Qb, const u16* __restrict__ Kb,
    const u16* __restrict__ Vb, const float* __restrict__ bkv,
    const float* __restrict__ bvv, u16* __restrict__ Mb)
{
    __shared__ u16 klds[KROWS * KSTR];

    const int tid = threadIdx.x;
    const int l0 = blockIdx.x * 16;        // 16 rows per block
    const int lb0 = l0 & (LBATCH - 1);     // row index within batch
    const int bbase = l0 - lb0;            // batch base row

    // Stage K rows [lb0-63, lb0+15] into LDS (bf16), skip virtual (g<0) rows.
    for (int idx = tid; idx < KROWS * 128; idx += 256) {
        const int gl = idx >> 7, c = idx & 127;
        const int g = lb0 - 63 + gl;
        if (g >= 0) {
            u32 v = *(const u32*)&Kb[(bbase + g) * D + c * 2];
            *(u32*)&klds[gl * KSTR + c * 2] = v;
        }
    }
    __syncthreads();

    const int wave = tid >> 6, lane = tid & 63;
    const float scale = 0.0625f;  // 1/sqrt(256)

    for (int rr = 0; rr < 4; ++rr) {
        const int widx = (wave << 2) + rr;   // 0..15
        const int r = l0 + widx;
        const int lbr = lb0 + widx;
        const u16* __restrict__ qrow = Qb + r * D;

        // ---- Phase A: lane j computes score j ----
        const int j = lane;
        const int g = lbr - 63 + j;
        float s;
        if (g >= 0) {
            const u16* krow = &klds[(widx + j) * KSTR];
            float acc = 0.f;
            #pragma unroll 8
            for (int d2 = 0; d2 < 128; ++d2) {
                u32 kw = *(const u32*)&krow[d2 * 2];
                u32 qw = *(const u32*)&qrow[d2 * 2];
                acc += bflo(kw) * bflo(qw) + bfhi(kw) * bfhi(qw);
            }
            s = acc;
        } else {
            float acc = 0.f;   // virtual key = bk
            #pragma unroll 8
            for (int d2 = 0; d2 < 128; ++d2) {
                u32 qw = *(const u32*)&qrow[d2 * 2];
                acc += bkv[d2 * 2] * bflo(qw) + bkv[d2 * 2 + 1] * bfhi(qw);
            }
            s = acc;
        }
        s *= scale;

        // ---- Phase B: nested softmax stats via shuffle reductions ----
        float m64 = s, m16 = s, m4 = s;
        #pragma unroll
        for (int o = 1; o < 64; o <<= 1) m64 = fmaxf(m64, __shfl_xor(m64, o));
        #pragma unroll
        for (int o = 1; o < 16; o <<= 1) m16 = fmaxf(m16, __shfl_xor(m16, o));
        #pragma unroll
        for (int o = 1; o < 4; o <<= 1)  m4  = fmaxf(m4,  __shfl_xor(m4,  o));
        float e64 = __expf(s - m64);
        float e16 = __expf(s - m16);
        float e4  = __expf(s - m4);
        float z64 = e64, z16 = e16, z4 = e4;
        #pragma unroll
        for (int o = 1; o < 64; o <<= 1) z64 += __shfl_xor(z64, o);
        #pragma unroll
        for (int o = 1; o < 16; o <<= 1) z16 += __shfl_xor(z16, o);
        #pragma unroll
        for (int o = 1; o < 4; o <<= 1)  z4  += __shfl_xor(z4,  o);
        const float Z16 = __shfl(z16, 63);   // stats of last 16-group (window 16)
        const float Z4  = __shfl(z4, 63);    // stats of last 4-group  (window 4)
        float w = e64 / z64;
        if (j >= 48) w += e16 / Z16;
        if (j >= 60) w += e4 / Z4;
        w *= (1.f / 3.f);

        // ---- Phase C: merged[l] = sum_j w_j * V[g_j], lane owns 4 dims ----
        float a0 = 0.f, a1 = 0.f, a2 = 0.f, a3 = 0.f;
        const int d0 = lane * 4;
        for (int jj = 0; jj < 64; ++jj) {
            const float wj = __shfl(w, jj);
            const int gj = lbr - 63 + jj;
            if (gj >= 0) {
                uint2 vv = *(const uint2*)&Vb[(bbase + gj) * D + d0];
                a0 += wj * bflo(vv.x); a1 += wj * bfhi(vv.x);
                a2 += wj * bflo(vv.y); a3 += wj * bfhi(vv.y);
            } else {           // virtual value = bv
                a0 += wj * bvv[d0 + 0]; a1 += wj * bvv[d0 + 1];
                a2 += wj * bvv[d0 + 2]; a3 += wj * bvv[d0 + 3];
            }
        }
        uint2 o;
        o.x = (u32)f2bf(a0) | ((u32)f2bf(a1) << 16);
        o.y = (u32)f2bf(a2) | ((u32)f2bf(a3) << 16);
        *(uint2*)&Mb[r * D + d0] = o;
    }
}

// ---------------- Kernel 3: output projection + residual ----------------
// out = H + merged @ Wo + bo
__global__ __launch_bounds__(256) void out_proj(
    const u16* __restrict__ Mb, const float* __restrict__ Wo,
    const float* __restrict__ bo, const float* __restrict__ H,
    float* __restrict__ out)
{
    __shared__ float As[64][37];
    __shared__ float Bs[32][64];

    const int tid = threadIdx.x;
    const int bx = blockIdx.x;     // 0..3
    const int by = blockIdx.y;     // 0..127
    const int row0 = by * 64;
    const int coln0 = bx * 64;

    const int tr = tid >> 4, tc = tid & 15;
    const int a_r = tid >> 2, a_k0 = (tid & 3) * 8;
    const int b_k = tid >> 3, b_c0 = (tid & 7) * 8;

    float acc[4][4] = {};

    for (int kb = 0; kb < D; kb += 32) {
        uint4 m = *(const uint4*)&Mb[(row0 + a_r) * D + kb + a_k0];
        float4 bw0 = *(const float4*)&Wo[(kb + b_k) * D + coln0 + b_c0];
        float4 bw1 = *(const float4*)&Wo[(kb + b_k) * D + coln0 + b_c0 + 4];
        As[a_r][a_k0 + 0] = bflo(m.x); As[a_r][a_k0 + 1] = bfhi(m.x);
        As[a_r][a_k0 + 2] = bflo(m.y); As[a_r][a_k0 + 3] = bfhi(m.y);
        As[a_r][a_k0 + 4] = bflo(m.z); As[a_r][a_k0 + 5] = bfhi(m.z);
        As[a_r][a_k0 + 6] = bflo(m.w); As[a_r][a_k0 + 7] = bfhi(m.w);
        *(float4*)&Bs[b_k][b_c0] = bw0;
        *(float4*)&Bs[b_k][b_c0 + 4] = bw1;
        __syncthreads();
        #pragma unroll 8
        for (int kk = 0; kk < 32; ++kk) {
            float a0 = As[tr * 4 + 0][kk];
            float a1 = As[tr * 4 + 1][kk];
            float a2 = As[tr * 4 + 2][kk];
            float a3 = As[tr * 4 + 3][kk];
            float4 b4 = *(const float4*)&Bs[kk][tc * 4];
            acc[0][0] += a0 * b4.x; acc[0][1] += a0 * b4.y; acc[0][2] += a0 * b4.z; acc[0][3] += a0 * b4.w;
            acc[1][0] += a1 * b4.x; acc[1][1] += a1 * b4.y; acc[1][2] += a1 * b4.z; acc[1][3] += a1 * b4.w;
            acc[2][0] += a2 * b4.x; acc[2][1] += a2 * b4.y; acc[2][2] += a2 * b4.z; acc[2][3] += a2 * b4.w;
            acc[3][0] += a3 * b4.x; acc[3][1] += a3 * b4.y; acc[3][2] += a3 * b4.z; acc[3][3] += a3 * b4.w;
        }
        __syncthreads();
    }

    #pragma unroll
    for (int ri = 0; ri < 4; ++ri) {
        const int row = row0 + tr * 4 + ri;
        const int col = coln0 + tc * 4;
        float4 bia = *(const float4*)&bo[col];
        float4 h   = *(const float4*)&H[row * D + col];
        float4 o;
        o.x = h.x + acc[ri][0] + bia.x;
        o.y = h.y + acc[ri][1] + bia.y;
        o.z = h.z + acc[ri][2] + bia.z;
        o.w = h.w + acc[ri][3] + bia.w;
        *(float4*)&out[row * D + col] = o;
    }
}

extern "C" void kernel_launch(void* const* d_in, const int* in_sizes, int n_in,
                              void* d_out, int out_size, void* d_ws, size_t ws_size,
                              hipStream_t stream) {
    const float* H  = (const float*)d_in[0];
    const float* Wq = (const float*)d_in[1];
    const float* bq = (const float*)d_in[2];
    const float* Wk = (const float*)d_in[3];
    const float* bk = (const float*)d_in[4];
    const float* Wv = (const float*)d_in[5];
    const float* bv = (const float*)d_in[6];
    const float* Wo = (const float*)d_in[7];
    const float* bo = (const float*)d_in[8];
    float* out = (float*)d_out;

    u16* Qb = (u16*)d_ws;
    u16* Kb = Qb + (size_t)NROWS * D;
    u16* Vb = Kb + (size_t)NROWS * D;
    u16* Mb = Vb + (size_t)NROWS * D;

    qkv_proj<<<dim3(12, 128), 256, 0, stream>>>(H, Wq, bq, Wk, bk, Wv, bv, Qb, Kb, Vb);
    attn_kernel<<<dim3(512), 256, 0, stream>>>(Qb, Kb, Vb, bk, bv, Mb);
    out_proj<<<dim3(4, 128), 256, 0, stream>>>(Mb, Wo, bo, H, out);
}

// Round 2
// 81.098 us; speedup vs baseline: 2.0918x; 2.0918x over previous
//
#include <hip/hip_runtime.h>
#include <hip/hip_bf16.h>

#define D 256
#define NROWS 8192
#define LBATCH 4096
#define LX 4160          // 4096 + 64 virtual prefix
#define VPAD 64

typedef unsigned int u32;
typedef unsigned short u16;

typedef short bf16x8 __attribute__((ext_vector_type(8)));
typedef float f32x4 __attribute__((ext_vector_type(4)));

__device__ __forceinline__ u16 f2bf(float f) {
    u32 x = __float_as_uint(f);
    x += 0x7fffu + ((x >> 16) & 1u);
    return (u16)(x >> 16);
}
__device__ __forceinline__ u32 pk2(float a, float b) {
    return (u32)f2bf(a) | ((u32)f2bf(b) << 16);
}

// ---------------- Kernel 0a: weight transpose+convert ----------------
// Wt[1024][256] bf16: rows 0..255=Wq^T, 256..511=Wk^T, 512..767=Wv^T, 768..1023=Wo^T
__global__ __launch_bounds__(256) void prep_wt(
    const float* __restrict__ Wq, const float* __restrict__ Wk,
    const float* __restrict__ Wv, const float* __restrict__ Wo,
    u16* __restrict__ Wt)
{
    const int o = blockIdx.x;      // 0..1023
    const int k = threadIdx.x;     // 0..255
    const float* src;
    int col;
    if (o < 256)      { src = Wq; col = o; }
    else if (o < 512) { src = Wk; col = o - 256; }
    else if (o < 768) { src = Wv; col = o - 512; }
    else              { src = Wo; col = o - 768; }
    Wt[o * 256 + k] = f2bf(src[k * 256 + col]);
}

// ---------------- Kernel 0b: virtual-key prefixes ----------------
__global__ __launch_bounds__(256) void fill_virt(
    const float* __restrict__ bk, const float* __restrict__ bv,
    u16* __restrict__ Kx, u16* __restrict__ Vt)
{
    const int bid = blockIdx.x;    // 0..255
    const int tid = threadIdx.x;
    if (bid < 128) {               // Kx prefix rows: 2 batches x 64 rows x 256
        const int b = bid >> 6, r = bid & 63;
        Kx[((size_t)b * LX + r) * 256 + tid] = f2bf(bk[tid]);
    } else {                       // Vt prefix cols: 2x256 dims x 64 cols
        const int vi = bid - 128;
        const int g = vi * 4 + (tid >> 6);   // 0..511
        const int b = g >> 8, dm = g & 255;
        const int c = tid & 63;
        Vt[((size_t)b * 256 + dm) * LX + c] = f2bf(bv[dm]);
    }
}

// ---------------- Kernel 1: QKV projection (MFMA) ----------------
// 64 rows x 128 cols per block over [8192 x 768]
__global__ __launch_bounds__(256) void qkv_mfma(
    const float* __restrict__ H, const u16* __restrict__ Wt,
    const float* __restrict__ bq, const float* __restrict__ bkb,
    const float* __restrict__ bvb,
    u16* __restrict__ Qb, u16* __restrict__ Kx, u16* __restrict__ Vt)
{
    __shared__ u16 As[64 * 256];

    const int tid = threadIdx.x;
    const int bx = blockIdx.x;     // 0..5
    const int by = blockIdx.y;     // 0..127
    const int row0 = by * 64;

    // stage A (fp32 -> bf16, XOR swizzle in 16B units)
    {
        const int r = tid >> 2, cb = (tid & 3) * 64;
        const float* hp = H + (size_t)(row0 + r) * 256 + cb;
        const int swz = (r & 7) << 3;
        #pragma unroll
        for (int i = 0; i < 16; ++i) {
            float4 h4 = *(const float4*)(hp + i * 4);
            uint2 pv; pv.x = pk2(h4.x, h4.y); pv.y = pk2(h4.z, h4.w);
            *(uint2*)(As + ((r * 256 + cb + i * 4) ^ swz)) = pv;
        }
    }
    __syncthreads();

    const int lane = tid & 63, w = tid >> 6;
    const int rowa = w * 16 + (lane & 15);
    const int kb = (lane >> 4) * 8;
    const int swa = (rowa & 7) << 3;

    bf16x8 af[8];
    #pragma unroll
    for (int ks = 0; ks < 8; ++ks)
        af[ks] = *(const bf16x8*)(As + ((rowa * 256 + ks * 32 + kb) ^ swa));

    f32x4 acc[8];
    #pragma unroll
    for (int i = 0; i < 8; ++i) acc[i] = (f32x4){0.f, 0.f, 0.f, 0.f};

    #pragma unroll
    for (int ks = 0; ks < 8; ++ks) {
        #pragma unroll
        for (int i = 0; i < 8; ++i) {
            bf16x8 bf = *(const bf16x8*)(Wt + (size_t)(bx * 128 + i * 16 + (lane & 15)) * 256 + ks * 32 + kb);
            acc[i] = __builtin_amdgcn_mfma_f32_16x16x32_bf16(af[ks], bf, acc[i], 0, 0, 0);
        }
    }

    const int mat = bx >> 1;   // 0=Q 1=K 2=V
    const float* bias = (mat == 0) ? bq : (mat == 1) ? bkb : bvb;
    const int rbase = row0 + w * 16 + (lane >> 4) * 4;

    #pragma unroll
    for (int i = 0; i < 8; ++i) {
        const int ncol = bx * 128 + i * 16 + (lane & 15);
        const int colm = ncol & 255;
        const float bi = bias[colm];
        if (mat == 2) {
            const int batch = rbase >> 12, lr = rbase & 4095;
            uint2 pv;
            pv.x = pk2(acc[i][0] + bi, acc[i][1] + bi);
            pv.y = pk2(acc[i][2] + bi, acc[i][3] + bi);
            *(uint2*)(Vt + ((size_t)batch * 256 + colm) * LX + VPAD + lr) = pv;
        } else {
            #pragma unroll
            for (int reg = 0; reg < 4; ++reg) {
                const int r = rbase + reg;
                const u16 v = f2bf(acc[i][reg] + bi);
                if (mat == 0) Qb[(size_t)r * 256 + colm] = v;
                else {
                    const int batch = r >> 12, lr = r & 4095;
                    Kx[((size_t)batch * LX + VPAD + lr) * 256 + colm] = v;
                }
            }
        }
    }
}

// ---------------- Kernel 2: fused 3-window attention (MFMA) ----------------
// 16 rows per block; keys local j in [0,80), band valid j in [ri+1, ri+64].
__global__ __launch_bounds__(256) void attn_mfma(
    const u16* __restrict__ Qb, const u16* __restrict__ Kx,
    const u16* __restrict__ Vt, u16* __restrict__ Mb)
{
    __shared__ u16 VtS[256 * 104];   // [dim][key], pad-104 stride
    __shared__ float Sb[16 * 80];    // raw scores*scale
    __shared__ u16 Pb[16 * 104];     // weights bf16, cols 80..95 zero

    const int tid = threadIdx.x;
    const int lane = tid & 63, w = tid >> 6;
    const int r0 = blockIdx.x * 16;
    const int batch = r0 >> 12;
    const int lb0 = r0 & 4095;

    // Issue Vt staging loads early (1 dim per thread, keys lb0..lb0+79)
    const u16* vsrc = Vt + ((size_t)batch * 256 + tid) * LX + lb0;
    uint4 sv[10];
    #pragma unroll
    for (int i = 0; i < 10; ++i) sv[i] = *(const uint4*)(vsrc + i * 8);

    // ---- QK^T (overlaps staging-load latency) ----
    const int kb = (lane >> 4) * 8;
    const u16* qp = Qb + (size_t)(r0 + (lane & 15)) * 256 + kb;
    bf16x8 qf[8];
    #pragma unroll
    for (int ks = 0; ks < 8; ++ks) qf[ks] = *(const bf16x8*)(qp + ks * 32);

    const u16* kp0 = Kx + ((size_t)batch * LX + lb0 + w * 16 + (lane & 15)) * 256 + kb;
    f32x4 acc0 = (f32x4){0.f, 0.f, 0.f, 0.f};
    #pragma unroll
    for (int ks = 0; ks < 8; ++ks) {
        bf16x8 kf = *(const bf16x8*)(kp0 + ks * 32);
        acc0 = __builtin_amdgcn_mfma_f32_16x16x32_bf16(qf[ks], kf, acc0, 0, 0, 0);
    }
    f32x4 acc1 = (f32x4){0.f, 0.f, 0.f, 0.f};
    if (w == 0) {
        const u16* kp1 = Kx + ((size_t)batch * LX + lb0 + 64 + (lane & 15)) * 256 + kb;
        #pragma unroll
        for (int ks = 0; ks < 8; ++ks) {
            bf16x8 kf = *(const bf16x8*)(kp1 + ks * 32);
            acc1 = __builtin_amdgcn_mfma_f32_16x16x32_bf16(qf[ks], kf, acc1, 0, 0, 0);
        }
    }

    const float scale = 0.0625f;
    #pragma unroll
    for (int reg = 0; reg < 4; ++reg) {
        const int ri = (lane >> 4) * 4 + reg;
        Sb[ri * 80 + w * 16 + (lane & 15)] = acc0[reg] * scale;
    }
    if (w == 0) {
        #pragma unroll
        for (int reg = 0; reg < 4; ++reg) {
            const int ri = (lane >> 4) * 4 + reg;
            Sb[ri * 80 + 64 + (lane & 15)] = acc1[reg] * scale;
        }
    }

    // Vt LDS writes (waits staging loads) + zero pad keys 80..95
    #pragma unroll
    for (int i = 0; i < 10; ++i) *(uint4*)(VtS + tid * 104 + i * 8) = sv[i];
    uint4 zz; zz.x = zz.y = zz.z = zz.w = 0u;
    *(uint4*)(VtS + tid * 104 + 80) = zz;
    *(uint4*)(VtS + tid * 104 + 88) = zz;
    __syncthreads();

    // ---- nested softmax: 4 rows/wave, 16 lanes/row, 5 cols/lane ----
    {
        const int ri = w * 4 + (lane >> 4);
        const int jb = lane & 15;
        float s5[5];
        float m = -1e30f;
        #pragma unroll
        for (int c = 0; c < 5; ++c) {
            const int j = jb + 16 * c;
            const float x = Sb[ri * 80 + j];
            const bool v = (j >= ri + 1) && (j <= ri + 64);
            s5[c] = v ? x : -1e30f;
            m = fmaxf(m, s5[c]);
        }
        #pragma unroll
        for (int o = 1; o < 16; o <<= 1) m = fmaxf(m, __shfl_xor(m, o));
        float e5[5], z64 = 0.f, z16 = 0.f, z4 = 0.f;
        #pragma unroll
        for (int c = 0; c < 5; ++c) {
            const int j = jb + 16 * c;
            const float e = __expf(s5[c] - m);   // invalid -> exp(-huge)=0
            e5[c] = e;
            z64 += e;
            if (j >= ri + 49) z16 += e;
            if (j >= ri + 61) z4 += e;
        }
        #pragma unroll
        for (int o = 1; o < 16; o <<= 1) {
            z64 += __shfl_xor(z64, o);
            z16 += __shfl_xor(z16, o);
            z4  += __shfl_xor(z4, o);
        }
        const float i64 = 1.f / z64, i16 = 1.f / z16, i4 = 1.f / z4;
        #pragma unroll
        for (int c = 0; c < 5; ++c) {
            const int j = jb + 16 * c;
            float wt = e5[c] * (i64 + (j >= ri + 49 ? i16 : 0.f) + (j >= ri + 61 ? i4 : 0.f)) * (1.f / 3.f);
            Pb[ri * 104 + j] = f2bf(wt);
        }
        Pb[ri * 104 + 80 + jb] = 0;
    }
    __syncthreads();

    // ---- PV: merged[16][256] = P[16][96] @ V[96][256] ----
    bf16x8 pa[3];
    #pragma unroll
    for (int ks = 0; ks < 3; ++ks)
        pa[ks] = *(const bf16x8*)(Pb + (lane & 15) * 104 + ks * 32 + kb);
    #pragma unroll
    for (int i = 0; i < 4; ++i) {
        const int c0 = (w * 4 + i) * 16;
        f32x4 acc = (f32x4){0.f, 0.f, 0.f, 0.f};
        #pragma unroll
        for (int ks = 0; ks < 3; ++ks) {
            bf16x8 vb = *(const bf16x8*)(VtS + (c0 + (lane & 15)) * 104 + ks * 32 + kb);
            acc = __builtin_amdgcn_mfma_f32_16x16x32_bf16(pa[ks], vb, acc, 0, 0, 0);
        }
        #pragma unroll
        for (int reg = 0; reg < 4; ++reg) {
            const int ri = (lane >> 4) * 4 + reg;
            Mb[(size_t)(r0 + ri) * 256 + c0 + (lane & 15)] = f2bf(acc[reg]);
        }
    }
}

// ---------------- Kernel 3: output projection + residual (MFMA) ----------------
__global__ __launch_bounds__(256) void out_mfma(
    const u16* __restrict__ Mb, const u16* __restrict__ Wt,
    const float* __restrict__ bo, const float* __restrict__ H,
    float* __restrict__ out)
{
    __shared__ u16 As[64 * 256];

    const int tid = threadIdx.x;
    const int bx = blockIdx.x;     // 0..1
    const int by = blockIdx.y;     // 0..127
    const int row0 = by * 64;

    {
        const int r = tid >> 2, cb = (tid & 3) * 64;
        const u16* mp = Mb + (size_t)(row0 + r) * 256 + cb;
        const int swz = (r & 7) << 3;
        #pragma unroll
        for (int i = 0; i < 8; ++i) {
            uint4 v = *(const uint4*)(mp + i * 8);
            *(uint4*)(As + ((r * 256 + cb + i * 8) ^ swz)) = v;
        }
    }
    __syncthreads();

    const int lane = tid & 63, w = tid >> 6;
    const int rowa = w * 16 + (lane & 15);
    const int kb = (lane >> 4) * 8;
    const int swa = (rowa & 7) << 3;

    bf16x8 af[8];
    #pragma unroll
    for (int ks = 0; ks < 8; ++ks)
        af[ks] = *(const bf16x8*)(As + ((rowa * 256 + ks * 32 + kb) ^ swa));

    f32x4 acc[8];
    #pragma unroll
    for (int i = 0; i < 8; ++i) acc[i] = (f32x4){0.f, 0.f, 0.f, 0.f};

    #pragma unroll
    for (int ks = 0; ks < 8; ++ks) {
        #pragma unroll
        for (int i = 0; i < 8; ++i) {
            bf16x8 bf = *(const bf16x8*)(Wt + (size_t)(768 + bx * 128 + i * 16 + (lane & 15)) * 256 + ks * 32 + kb);
            acc[i] = __builtin_amdgcn_mfma_f32_16x16x32_bf16(af[ks], bf, acc[i], 0, 0, 0);
        }
    }

    #pragma unroll
    for (int i = 0; i < 8; ++i) {
        const int col = bx * 128 + i * 16 + (lane & 15);
        const float bi = bo[col];
        #pragma unroll
        for (int reg = 0; reg < 4; ++reg) {
            const int r = row0 + w * 16 + (lane >> 4) * 4 + reg;
            const size_t off = (size_t)r * 256 + col;
            out[off] = H[off] + acc[i][reg] + bi;
        }
    }
}

extern "C" void kernel_launch(void* const* d_in, const int* in_sizes, int n_in,
                              void* d_out, int out_size, void* d_ws, size_t ws_size,
                              hipStream_t stream) {
    const float* H  = (const float*)d_in[0];
    const float* Wq = (const float*)d_in[1];
    const float* bq = (const float*)d_in[2];
    const float* Wk = (const float*)d_in[3];
    const float* bk = (const float*)d_in[4];
    const float* Wv = (const float*)d_in[5];
    const float* bv = (const float*)d_in[6];
    const float* Wo = (const float*)d_in[7];
    const float* bo = (const float*)d_in[8];
    float* out = (float*)d_out;

    u16* Wt = (u16*)d_ws;                          // 1024*256
    u16* Qb = Wt + 1024 * 256;                     // 8192*256
    u16* Kx = Qb + (size_t)NROWS * 256;            // 2*4160*256
    u16* Vt = Kx + (size_t)2 * LX * 256;           // 2*256*4160
    u16* Mb = Vt + (size_t)2 * 256 * LX;           // 8192*256

    prep_wt<<<1024, 256, 0, stream>>>(Wq, Wk, Wv, Wo, Wt);
    fill_virt<<<256, 256, 0, stream>>>(bk, bv, Kx, Vt);
    qkv_mfma<<<dim3(6, 128), 256, 0, stream>>>(H, Wt, bq, bk, bv, Qb, Kx, Vt);
    attn_mfma<<<512, 256, 0, stream>>>(Qb, Kx, Vt, Mb);
    out_mfma<<<dim3(2, 128), 256, 0, stream>>>(Mb, Wt, bo, H, out);
}

// Round 4
// 59.451 us; speedup vs baseline: 2.8535x; 1.3641x over previous
//
#include <hip/hip_runtime.h>
#include <hip/hip_bf16.h>

#define D 256
#define NROWS 8192
#define LBATCH 4096
#define LX 4160          // 4096 + 64 virtual prefix
#define VPAD 64

#define QBLK 32          // attn rows per block
#define KKEYS 96         // staged keys per block (3 x 32 MFMA k-steps)
#define VSTR 104         // VtS row stride (u16) -> 52 dw, 2-way max
#define SSTR 100         // Sb row stride (f32)
#define PSTR 104         // Pb row stride (u16)

typedef unsigned int u32;
typedef unsigned short u16;

typedef short bf16x8 __attribute__((ext_vector_type(8)));
typedef float f32x4 __attribute__((ext_vector_type(4)));

__device__ __forceinline__ u16 f2bf(float f) {
    u32 x = __float_as_uint(f);
    x += 0x7fffu + ((x >> 16) & 1u);
    return (u16)(x >> 16);
}
__device__ __forceinline__ u32 pk2(float a, float b) {
    return (u32)f2bf(a) | ((u32)f2bf(b) << 16);
}

// ---------------- Kernel 0: prep (weight transpose + virtual prefixes) ----------------
// blocks 0..63: LDS-transpose 64x64 tiles of Wq/Wk/Wv/Wo into Wt (bf16, [out][in])
// blocks 64..79: Kx virtual prefix rows = bk ; blocks 80..95: Vt prefix cols = bv
__global__ __launch_bounds__(256) void prep(
    const float* __restrict__ Wq, const float* __restrict__ Wk,
    const float* __restrict__ Wv, const float* __restrict__ Wo,
    const float* __restrict__ bk, const float* __restrict__ bv,
    u16* __restrict__ Wt, u16* __restrict__ Kx, u16* __restrict__ Vt)
{
    const int b = blockIdx.x, t = threadIdx.x;
    if (b < 64) {
        __shared__ float T[64][69];
        const int m = b >> 4, tile = b & 15;
        const int k0 = (tile >> 2) * 64, o0 = (tile & 3) * 64;
        const float* __restrict__ W = (m == 0) ? Wq : (m == 1) ? Wk : (m == 2) ? Wv : Wo;
        const int r = t >> 2, c0 = (t & 3) * 16;
        #pragma unroll
        for (int j = 0; j < 4; ++j) {
            float4 v = *(const float4*)&W[(k0 + r) * 256 + o0 + c0 + j * 4];
            T[r][c0 + j * 4 + 0] = v.x; T[r][c0 + j * 4 + 1] = v.y;
            T[r][c0 + j * 4 + 2] = v.z; T[r][c0 + j * 4 + 3] = v.w;
        }
        __syncthreads();
        const int orow = t >> 2, ck0 = (t & 3) * 16;
        float tv[16];
        #pragma unroll
        for (int j = 0; j < 16; ++j) tv[j] = T[ck0 + j][orow];
        u32 pw[8];
        #pragma unroll
        for (int j = 0; j < 8; ++j) pw[j] = pk2(tv[2 * j], tv[2 * j + 1]);
        // FIX (R3 bug): destination row must include the per-matrix offset m*256.
        uint4* dst = (uint4*)&Wt[(size_t)(m * 256 + o0 + orow) * 256 + k0 + ck0];
        dst[0] = *(uint4*)&pw[0];
        dst[1] = *(uint4*)&pw[4];
    } else if (b < 80) {
        const int g = (b - 64) * 256 + t;          // 0..4095
        const int batch = g >> 11, rem = g & 2047;
        const int r = rem >> 5, c8 = rem & 31;
        float4 f0 = *(const float4*)&bk[c8 * 8];
        float4 f1 = *(const float4*)&bk[c8 * 8 + 4];
        uint4 o;
        o.x = pk2(f0.x, f0.y); o.y = pk2(f0.z, f0.w);
        o.z = pk2(f1.x, f1.y); o.w = pk2(f1.z, f1.w);
        *(uint4*)&Kx[((size_t)batch * LX + r) * 256 + c8 * 8] = o;
    } else {
        const int g = (b - 80) * 256 + t;          // 0..4095
        const int batch = g >> 11, rem = g & 2047;
        const int d = rem >> 3, seg = rem & 7;
        const u16 val = f2bf(bv[d]);
        const u32 vv = (u32)val | ((u32)val << 16);
        uint4 o; o.x = vv; o.y = vv; o.z = vv; o.w = vv;
        *(uint4*)&Vt[((size_t)batch * 256 + d) * LX + seg * 8] = o;
    }
}

// ---------------- Kernel 1: QKV projection (MFMA, LDS-staged A and B) ----------------
// 64 rows x 128 cols per block over [8192 x 768]
__global__ __launch_bounds__(256) void qkv_mfma(
    const float* __restrict__ H, const u16* __restrict__ Wt,
    const float* __restrict__ bq, const float* __restrict__ bkb,
    const float* __restrict__ bvb,
    u16* __restrict__ Qb, u16* __restrict__ Kx, u16* __restrict__ Vt)
{
    __shared__ u16 As[64 * 256];
    __shared__ u16 Bs[2][128 * 68];

    const int tid = threadIdx.x;
    const int bx = blockIdx.x;     // 0..5
    const int by = blockIdx.y;     // 0..127
    const int row0 = by * 64;
    const u16* __restrict__ wb = Wt + (size_t)(bx * 128) * 256;

    uint4 breg[4];
    // issue B slice 0 loads (coalesced: 8 threads cover one col's 128B)
    #pragma unroll
    for (int i = 0; i < 4; ++i) {
        const int u = i * 256 + tid, col = u >> 3, seg = u & 7;
        breg[i] = *(const uint4*)&wb[col * 256 + seg * 8];
    }
    // stage A (fp32 -> bf16, XOR swizzle in 8-u16 units)
    {
        const int r = tid >> 2, cb = (tid & 3) * 64;
        const float* hp = H + (size_t)(row0 + r) * 256 + cb;
        const int swz = (r & 7) << 3;
        #pragma unroll
        for (int i = 0; i < 16; ++i) {
            float4 h4 = *(const float4*)(hp + i * 4);
            uint2 pv; pv.x = pk2(h4.x, h4.y); pv.y = pk2(h4.z, h4.w);
            *(uint2*)(As + ((r * 256 + cb + i * 4) ^ swz)) = pv;
        }
    }
    #pragma unroll
    for (int i = 0; i < 4; ++i) {
        const int u = i * 256 + tid, col = u >> 3, seg = u & 7;
        *(uint4*)&Bs[0][col * 68 + seg * 8] = breg[i];
    }
    __syncthreads();

    const int lane = tid & 63, w = tid >> 6;
    const int l15 = lane & 15, lhi = lane >> 4;
    const int rowa = w * 16 + l15;
    const int kb = lhi * 8;
    const int swa = (rowa & 7) << 3;

    bf16x8 af[8];
    #pragma unroll
    for (int ks = 0; ks < 8; ++ks)
        af[ks] = *(const bf16x8*)(As + ((rowa * 256 + ks * 32 + kb) ^ swa));

    f32x4 acc[8];
    #pragma unroll
    for (int i = 0; i < 8; ++i) acc[i] = (f32x4){0.f, 0.f, 0.f, 0.f};

    for (int s = 0; s < 4; ++s) {
        if (s < 3) {
            #pragma unroll
            for (int i = 0; i < 4; ++i) {
                const int u = i * 256 + tid, col = u >> 3, seg = u & 7;
                breg[i] = *(const uint4*)&wb[col * 256 + (s + 1) * 64 + seg * 8];
            }
        }
        #pragma unroll
        for (int ks2 = 0; ks2 < 2; ++ks2) {
            const int ks = s * 2 + ks2;
            #pragma unroll
            for (int i = 0; i < 8; ++i) {
                bf16x8 bf = *(const bf16x8*)&Bs[s & 1][(i * 16 + l15) * 68 + ks2 * 32 + kb];
                acc[i] = __builtin_amdgcn_mfma_f32_16x16x32_bf16(af[ks], bf, acc[i], 0, 0, 0);
            }
        }
        if (s < 3) {
            __syncthreads();
            #pragma unroll
            for (int i = 0; i < 4; ++i) {
                const int u = i * 256 + tid, col = u >> 3, seg = u & 7;
                *(uint4*)&Bs[(s + 1) & 1][col * 68 + seg * 8] = breg[i];
            }
            __syncthreads();
        }
    }

    const int mat = bx >> 1;   // 0=Q 1=K 2=V
    const float* bias = (mat == 0) ? bq : (mat == 1) ? bkb : bvb;
    const int rbase = row0 + w * 16 + lhi * 4;

    #pragma unroll
    for (int i = 0; i < 8; ++i) {
        const int ncol = bx * 128 + i * 16 + l15;
        const int colm = ncol & 255;
        const float bi = bias[colm];
        if (mat == 2) {
            const int batch = rbase >> 12, lr = rbase & 4095;
            uint2 pv;
            pv.x = pk2(acc[i][0] + bi, acc[i][1] + bi);
            pv.y = pk2(acc[i][2] + bi, acc[i][3] + bi);
            *(uint2*)(Vt + ((size_t)batch * 256 + colm) * LX + VPAD + lr) = pv;
        } else {
            #pragma unroll
            for (int reg = 0; reg < 4; ++reg) {
                const int r = rbase + reg;
                const u16 v = f2bf(acc[i][reg] + bi);
                if (mat == 0) Qb[(size_t)r * 256 + colm] = v;
                else {
                    const int batch = r >> 12, lr = r & 4095;
                    Kx[((size_t)batch * LX + VPAD + lr) * 256 + colm] = v;
                }
            }
        }
    }
}

// ---------------- Kernel 2: fused 3-window attention (MFMA, all-LDS operands) ----------------
// 32 rows/block, 512 threads, 96 staged keys. local j = vtcol - lb0;
// valid j for row ri: [ri+1, ri+64]; w16: [ri+49,..]; w4: [ri+61,..].
__global__ __launch_bounds__(512) void attn_mfma(
    const u16* __restrict__ Qb, const u16* __restrict__ Kx,
    const u16* __restrict__ Vt, u16* __restrict__ Mb)
{
    __shared__ u16 Ks[KKEYS * 256];       // XOR-swizzled [key][feat]
    __shared__ u16 VtS[256 * VSTR];       // [dim][key]
    __shared__ float Sb[QBLK * SSTR];
    __shared__ u16 Pb[QBLK * PSTR];

    const int tid = threadIdx.x;
    const int lane = tid & 63, w = tid >> 6;
    const int l15 = lane & 15, lhi = lane >> 4;
    const int r0 = blockIdx.x * QBLK;
    const int batch = r0 >> 12;
    const int lb0 = r0 & 4095;
    const size_t kbase = (size_t)batch * LX + lb0;

    // ---- issue staging loads (coalesced) ----
    uint4 kreg[6], vreg[6];
    #pragma unroll
    for (int i = 0; i < 6; ++i) {
        const int u = i * 512 + tid;
        const int row = u >> 5, seg = u & 31;
        kreg[i] = *(const uint4*)&Kx[(kbase + row) * 256 + seg * 8];
    }
    #pragma unroll
    for (int i = 0; i < 6; ++i) {
        const int u = i * 512 + tid;
        const int d = (u * 21846) >> 18;       // u/12
        const int seg = u - d * 12;
        vreg[i] = *(const uint4*)&Vt[((size_t)batch * 256 + d) * LX + lb0 + seg * 8];
    }
    // ---- LDS writes ----
    #pragma unroll
    for (int i = 0; i < 6; ++i) {
        const int u = i * 512 + tid;
        const int row = u >> 5, seg = u & 31;
        *(uint4*)&Ks[row * 256 + (seg ^ (row & 7)) * 8] = kreg[i];
    }
    #pragma unroll
    for (int i = 0; i < 6; ++i) {
        const int u = i * 512 + tid;
        const int d = (u * 21846) >> 18;
        const int seg = u - d * 12;
        *(uint4*)&VtS[d * VSTR + seg * 8] = vreg[i];
    }
    __syncthreads();

    // ---- QK^T: 12 C-tiles (2 rowtiles x 6 keytiles) over 8 waves ----
    const float scale = 0.0625f;
    #pragma unroll
    for (int pass = 0; pass < 2; ++pass) {
        const int T = (pass == 0) ? w : w + 8;
        if (pass == 1 && w >= 4) break;
        const int rt = (T >= 6) ? 1 : 0;
        const int kt = T - rt * 6;
        const u16* qp = Qb + (size_t)(r0 + rt * 16 + l15) * 256;
        const int key = kt * 16 + l15;
        f32x4 acc = (f32x4){0.f, 0.f, 0.f, 0.f};
        #pragma unroll
        for (int ks = 0; ks < 8; ++ks) {
            bf16x8 qf = *(const bf16x8*)(qp + ks * 32 + lhi * 8);
            bf16x8 kf = *(const bf16x8*)&Ks[key * 256 + ((ks * 4 + lhi) ^ (key & 7)) * 8];
            acc = __builtin_amdgcn_mfma_f32_16x16x32_bf16(qf, kf, acc, 0, 0, 0);
        }
        #pragma unroll
        for (int reg = 0; reg < 4; ++reg)
            Sb[(rt * 16 + lhi * 4 + reg) * SSTR + kt * 16 + l15] = acc[reg] * scale;
    }
    __syncthreads();

    // ---- nested softmax: 32 rows x 16 lanes, 6 cols/lane ----
    {
        const int ri = w * 4 + lhi;
        const int jb = l15;
        float s6[6];
        float m = -1e30f;
        #pragma unroll
        for (int c = 0; c < 6; ++c) {
            const int j = jb + 16 * c;
            const float x = Sb[ri * SSTR + j];
            const bool v = (j >= ri + 1) && (j <= ri + 64);
            s6[c] = v ? x : -1e30f;
            m = fmaxf(m, s6[c]);
        }
        #pragma unroll
        for (int o = 1; o < 16; o <<= 1) m = fmaxf(m, __shfl_xor(m, o));
        float e6[6], z64 = 0.f, z16 = 0.f, z4 = 0.f;
        #pragma unroll
        for (int c = 0; c < 6; ++c) {
            const int j = jb + 16 * c;
            const float e = __expf(s6[c] - m);
            e6[c] = e;
            z64 += e;
            if (j >= ri + 49) z16 += e;
            if (j >= ri + 61) z4 += e;
        }
        #pragma unroll
        for (int o = 1; o < 16; o <<= 1) {
            z64 += __shfl_xor(z64, o);
            z16 += __shfl_xor(z16, o);
            z4  += __shfl_xor(z4, o);
        }
        const float i64 = 1.f / z64, i16 = 1.f / z16, i4 = 1.f / z4;
        #pragma unroll
        for (int c = 0; c < 6; ++c) {
            const int j = jb + 16 * c;
            float wt = e6[c] * (i64 + (j >= ri + 49 ? i16 : 0.f) + (j >= ri + 61 ? i4 : 0.f)) * (1.f / 3.f);
            Pb[ri * PSTR + j] = f2bf(wt);
        }
    }
    __syncthreads();

    // ---- PV: merged[32][256] = P[32][96] @ V[96][256]; wave w -> dims [w*32, w*32+32) ----
    #pragma unroll
    for (int rt = 0; rt < 2; ++rt) {
        bf16x8 pa[3];
        #pragma unroll
        for (int ks = 0; ks < 3; ++ks)
            pa[ks] = *(const bf16x8*)&Pb[(rt * 16 + l15) * PSTR + ks * 32 + lhi * 8];
        #pragma unroll
        for (int dd = 0; dd < 2; ++dd) {
            const int dt = w * 2 + dd;
            f32x4 acc = (f32x4){0.f, 0.f, 0.f, 0.f};
            #pragma unroll
            for (int ks = 0; ks < 3; ++ks) {
                bf16x8 vb = *(const bf16x8*)&VtS[(dt * 16 + l15) * VSTR + ks * 32 + lhi * 8];
                acc = __builtin_amdgcn_mfma_f32_16x16x32_bf16(pa[ks], vb, acc, 0, 0, 0);
            }
            #pragma unroll
            for (int reg = 0; reg < 4; ++reg)
                Mb[(size_t)(r0 + rt * 16 + lhi * 4 + reg) * 256 + dt * 16 + l15] = f2bf(acc[reg]);
        }
    }
}

// ---------------- Kernel 3: output projection + residual (MFMA, LDS A+B) ----------------
__global__ __launch_bounds__(256) void out_mfma(
    const u16* __restrict__ Mb, const u16* __restrict__ Wt,
    const float* __restrict__ bo, const float* __restrict__ H,
    float* __restrict__ out)
{
    __shared__ u16 As[64 * 256];
    __shared__ u16 Bs[2][128 * 68];

    const int tid = threadIdx.x;
    const int bx = blockIdx.x;     // 0..1
    const int by = blockIdx.y;     // 0..127
    const int row0 = by * 64;
    const u16* __restrict__ wb = Wt + (size_t)(768 + bx * 128) * 256;

    uint4 breg[4];
    #pragma unroll
    for (int i = 0; i < 4; ++i) {
        const int u = i * 256 + tid, col = u >> 3, seg = u & 7;
        breg[i] = *(const uint4*)&wb[col * 256 + seg * 8];
    }
    {
        const int r = tid >> 2, cb = (tid & 3) * 64;
        const u16* mp = Mb + (size_t)(row0 + r) * 256 + cb;
        const int swz = (r & 7) << 3;
        #pragma unroll
        for (int i = 0; i < 8; ++i) {
            uint4 v = *(const uint4*)(mp + i * 8);
            *(uint4*)(As + ((r * 256 + cb + i * 8) ^ swz)) = v;
        }
    }
    #pragma unroll
    for (int i = 0; i < 4; ++i) {
        const int u = i * 256 + tid, col = u >> 3, seg = u & 7;
        *(uint4*)&Bs[0][col * 68 + seg * 8] = breg[i];
    }
    __syncthreads();

    const int lane = tid & 63, w = tid >> 6;
    const int l15 = lane & 15, lhi = lane >> 4;
    const int rowa = w * 16 + l15;
    const int kb = lhi * 8;
    const int swa = (rowa & 7) << 3;

    bf16x8 af[8];
    #pragma unroll
    for (int ks = 0; ks < 8; ++ks)
        af[ks] = *(const bf16x8*)(As + ((rowa * 256 + ks * 32 + kb) ^ swa));

    f32x4 acc[8];
    #pragma unroll
    for (int i = 0; i < 8; ++i) acc[i] = (f32x4){0.f, 0.f, 0.f, 0.f};

    for (int s = 0; s < 4; ++s) {
        if (s < 3) {
            #pragma unroll
            for (int i = 0; i < 4; ++i) {
                const int u = i * 256 + tid, col = u >> 3, seg = u & 7;
                breg[i] = *(const uint4*)&wb[col * 256 + (s + 1) * 64 + seg * 8];
            }
        }
        #pragma unroll
        for (int ks2 = 0; ks2 < 2; ++ks2) {
            const int ks = s * 2 + ks2;
            #pragma unroll
            for (int i = 0; i < 8; ++i) {
                bf16x8 bf = *(const bf16x8*)&Bs[s & 1][(i * 16 + l15) * 68 + ks2 * 32 + kb];
                acc[i] = __builtin_amdgcn_mfma_f32_16x16x32_bf16(af[ks], bf, acc[i], 0, 0, 0);
            }
        }
        if (s < 3) {
            __syncthreads();
            #pragma unroll
            for (int i = 0; i < 4; ++i) {
                const int u = i * 256 + tid, col = u >> 3, seg = u & 7;
                *(uint4*)&Bs[(s + 1) & 1][col * 68 + seg * 8] = breg[i];
            }
            __syncthreads();
        }
    }

    #pragma unroll
    for (int i = 0; i < 8; ++i) {
        const int col = bx * 128 + i * 16 + l15;
        const float bi = bo[col];
        #pragma unroll
        for (int reg = 0; reg < 4; ++reg) {
            const int r = row0 + w * 16 + lhi * 4 + reg;
            const size_t off = (size_t)r * 256 + col;
            out[off] = H[off] + acc[i][reg] + bi;
        }
    }
}

extern "C" void kernel_launch(void* const* d_in, const int* in_sizes, int n_in,
                              void* d_out, int out_size, void* d_ws, size_t ws_size,
                              hipStream_t stream) {
    const float* H  = (const float*)d_in[0];
    const float* Wq = (const float*)d_in[1];
    const float* bq = (const float*)d_in[2];
    const float* Wk = (const float*)d_in[3];
    const float* bk = (const float*)d_in[4];
    const float* Wv = (const float*)d_in[5];
    const float* bv = (const float*)d_in[6];
    const float* Wo = (const float*)d_in[7];
    const float* bo = (const float*)d_in[8];
    float* out = (float*)d_out;

    u16* Wt = (u16*)d_ws;                          // 1024*256
    u16* Qb = Wt + 1024 * 256;                     // 8192*256
    u16* Kx = Qb + (size_t)NROWS * 256;            // 2*4160*256
    u16* Vt = Kx + (size_t)2 * LX * 256;           // 2*256*4160
    u16* Mb = Vt + (size_t)2 * 256 * LX;           // 8192*256

    prep<<<96, 256, 0, stream>>>(Wq, Wk, Wv, Wo, bk, bv, Wt, Kx, Vt);
    qkv_mfma<<<dim3(6, 128), 256, 0, stream>>>(H, Wt, bq, bk, bv, Qb, Kx, Vt);
    attn_mfma<<<256, 512, 0, stream>>>(Qb, Kx, Vt, Mb);
    out_mfma<<<dim3(2, 128), 256, 0, stream>>>(Mb, Wt, bo, H, out);
}